// Round 1
// baseline (88.434 us; speedup 1.0000x reference)
//
#include <hip/hip_runtime.h>

// out[n,p] = sum_{k=0..7} X[n, p+k] * W[p*8 + k] + b[p],  X zero-padded past P.
// N=1024, P=20000, K=8, LF=1. All fp32. Memory-bound (~161 MB min HBM traffic).

constexpr int N = 1024;
constexpr int P = 20000;
constexpr int K = 8;
constexpr int P4 = P / 4;          // 5000 float4 columns per row

__global__ __launch_bounds__(256)
void local_linear_kernel(const float* __restrict__ X,
                         const float* __restrict__ W,
                         const float* __restrict__ b,
                         float* __restrict__ out) {
    int tid = blockIdx.x * blockDim.x + threadIdx.x;
    constexpr int total = N * P4;
    if (tid >= total) return;

    int n = tid / P4;
    int q = tid - n * P4;          // float4 column index in [0, 5000)
    int p = q * 4;                 // starting p for this thread

    const float* xrow = X + (size_t)n * P;

    // Need X[n, p .. p+10]; load 12 floats (3 x float4) on the fast path.
    float xv[12];
    if (p + 12 <= P) {
        float4 a = *reinterpret_cast<const float4*>(xrow + p);
        float4 c = *reinterpret_cast<const float4*>(xrow + p + 4);
        float4 d = *reinterpret_cast<const float4*>(xrow + p + 8);
        xv[0] = a.x; xv[1] = a.y; xv[2]  = a.z; xv[3]  = a.w;
        xv[4] = c.x; xv[5] = c.y; xv[6]  = c.z; xv[7]  = c.w;
        xv[8] = d.x; xv[9] = d.y; xv[10] = d.z; xv[11] = d.w;
    } else {
        // Tail: bounds-checked scalar loads, zero past P (matches jnp.pad).
        #pragma unroll
        for (int i = 0; i < 12; ++i)
            xv[i] = (p + i < P) ? xrow[p + i] : 0.0f;
    }

    // W rows p..p+3: 32 contiguous floats, 128B-aligned (p % 4 == 0).
    const float* wp = W + (size_t)p * K;
    float wv[32];
    #pragma unroll
    for (int i = 0; i < 8; ++i) {
        float4 w4 = *reinterpret_cast<const float4*>(wp + i * 4);
        wv[i * 4 + 0] = w4.x;
        wv[i * 4 + 1] = w4.y;
        wv[i * 4 + 2] = w4.z;
        wv[i * 4 + 3] = w4.w;
    }

    float4 bv = *reinterpret_cast<const float4*>(b + p);

    float r[4];
    #pragma unroll
    for (int j = 0; j < 4; ++j) {
        float s = 0.0f;
        #pragma unroll
        for (int k = 0; k < K; ++k)
            s += xv[j + k] * wv[j * K + k];
        r[j] = s;
    }

    float4 o;
    o.x = r[0] + bv.x;
    o.y = r[1] + bv.y;
    o.z = r[2] + bv.z;
    o.w = r[3] + bv.w;
    *reinterpret_cast<float4*>(out + (size_t)n * P + p) = o;
}

extern "C" void kernel_launch(void* const* d_in, const int* in_sizes, int n_in,
                              void* d_out, int out_size, void* d_ws, size_t ws_size,
                              hipStream_t stream) {
    const float* X = (const float*)d_in[0];
    const float* W = (const float*)d_in[1];
    const float* b = (const float*)d_in[2];
    float* out = (float*)d_out;

    constexpr int total_threads = N * P4;          // 5,120,000
    constexpr int block = 256;
    constexpr int grid = (total_threads + block - 1) / block;  // 20,000

    local_linear_kernel<<<grid, block, 0, stream>>>(X, W, b, out);
}

// Round 2
// 35.136 us; speedup vs baseline: 2.5169x; 2.5169x over previous
//
#include <hip/hip_runtime.h>

// out[n,p] = sum_{k=0..7} X[n, p+k] * W[p*8 + k] + b[p],  X zero-padded past P.
// N=1024, P=20000, K=8, LF=1. fp32.
//
// Round-1 lesson: per-row W loads are 128B-strided per lane -> 64 cache lines
// per dwordx4 instruction -> TA/L1-throughput bound (~550 cyc/wave, 93% of it W).
// Fix: thread owns 4 fixed p-columns, keeps W(32f)+b(4f) in REGISTERS, loops
// over ROWS rows. W strided cost paid once per kernel, not once per row.

constexpr int N  = 1024;
constexpr int P  = 20000;
constexpr int K  = 8;
constexpr int P4 = P / 4;              // 5000 column-groups of 4
constexpr int COLS_PADDED = 5120;      // pad to full waves (5120 = 80 waves)
constexpr int NCHUNKS = 64;            // row-chunks (n-splits)
constexpr int ROWS = N / NCHUNKS;      // 16 rows per thread

__global__ __launch_bounds__(256)
void local_linear_kernel(const float* __restrict__ X,
                         const float* __restrict__ W,
                         const float* __restrict__ b,
                         float* __restrict__ out) {
    int tid   = blockIdx.x * blockDim.x + threadIdx.x;
    int chunk = tid / COLS_PADDED;         // which block of 16 rows
    int q     = tid - chunk * COLS_PADDED; // column-group index
    if (q >= P4) return;                   // padding lanes (wave-uniform)

    int p  = q * 4;
    int n0 = chunk * ROWS;

    // ---- one-time register staging: W rows p..p+3 (32 floats) + b ----
    const float* wp = W + (size_t)p * K;   // 128B-aligned, contiguous 128B
    float wv[32];
    #pragma unroll
    for (int i = 0; i < 8; ++i) {
        float4 w4 = *reinterpret_cast<const float4*>(wp + i * 4);
        wv[i * 4 + 0] = w4.x;
        wv[i * 4 + 1] = w4.y;
        wv[i * 4 + 2] = w4.z;
        wv[i * 4 + 3] = w4.w;
    }
    float4 bv = *reinterpret_cast<const float4*>(b + p);

    const bool interior = (p + 12 <= P);   // uniform per thread across rows

    // ---- row loop: only coalesced traffic (3 loads + 1 store per row) ----
    for (int r = 0; r < ROWS; ++r) {
        const float* xrow = X + (size_t)(n0 + r) * P;

        float xv[12];
        if (interior) {
            float4 a = *reinterpret_cast<const float4*>(xrow + p);
            float4 c = *reinterpret_cast<const float4*>(xrow + p + 4);
            float4 d = *reinterpret_cast<const float4*>(xrow + p + 8);
            xv[0] = a.x; xv[1] = a.y; xv[2]  = a.z; xv[3]  = a.w;
            xv[4] = c.x; xv[5] = c.y; xv[6]  = c.z; xv[7]  = c.w;
            xv[8] = d.x; xv[9] = d.y; xv[10] = d.z; xv[11] = d.w;
        } else {
            #pragma unroll
            for (int i = 0; i < 12; ++i)
                xv[i] = (p + i < P) ? xrow[p + i] : 0.0f;  // matches jnp.pad
        }

        float r0 = bv.x, r1 = bv.y, r2 = bv.z, r3 = bv.w;
        #pragma unroll
        for (int k = 0; k < K; ++k) {
            r0 += xv[0 + k] * wv[0  + k];
            r1 += xv[1 + k] * wv[8  + k];
            r2 += xv[2 + k] * wv[16 + k];
            r3 += xv[3 + k] * wv[24 + k];
        }

        float4 o; o.x = r0; o.y = r1; o.z = r2; o.w = r3;
        *reinterpret_cast<float4*>(out + (size_t)(n0 + r) * P + p) = o;
    }
}

extern "C" void kernel_launch(void* const* d_in, const int* in_sizes, int n_in,
                              void* d_out, int out_size, void* d_ws, size_t ws_size,
                              hipStream_t stream) {
    const float* X = (const float*)d_in[0];
    const float* W = (const float*)d_in[1];
    const float* b = (const float*)d_in[2];
    float* out = (float*)d_out;

    constexpr int total_threads = COLS_PADDED * NCHUNKS;  // 327,680
    constexpr int block = 256;
    constexpr int grid = total_threads / block;           // 1,280 blocks

    local_linear_kernel<<<grid, block, 0, stream>>>(X, W, b, out);
}